// Round 9
// baseline (174.740 us; speedup 1.0000x reference)
//
#include <hip/hip_runtime.h>

#define BGRAPH  16
#define NPG     8192     // 2^13 nodes per graph
#define DIM     256
#define KKEEP   4096     // 2^12 kept per graph
#define TOTALN  (BGRAPH * NPG)     // 131072
#define TOTKEEP (BGRAPH * KKEEP)   // 65536
#define NEDGE   2097152
#define NBUCK   8192     // 13-bit buckets

using u16 = unsigned short;
using u32 = unsigned int;

// descending-sortable transform of f32 bits: smaller kd <=> larger float
__device__ __forceinline__ u32 desc_key(float f) {
  u32 b = __float_as_uint(f);
  u32 s = b ^ ((b & 0x80000000u) ? 0xFFFFFFFFu : 0x80000000u);  // asc-sortable
  return ~s;                                                     // desc-sortable
}

// ---------------- kernel 0: zero ghist --------------------------------------
__global__ __launch_bounds__(512) void k_zero(u32* __restrict__ ghist) {
  ghist[blockIdx.x * 512 + threadIdx.x] = 0u;
}

// ---------------- kernel 1: score + fused fire-and-forget histogram ---------
// one wave per row. lane0 stores score and bumps the bucket counter; the
// atomicAdd result is unused -> no wave stall, hot-line serialization is
// hidden under the 134 MB streaming read.
__global__ __launch_bounds__(256) void k_score(const float* __restrict__ x,
                                               const float* __restrict__ w,
                                               float* __restrict__ score,
                                               u32* __restrict__ ghist) {
  int gid  = blockIdx.x * 256 + threadIdx.x;
  int row  = gid >> 6;
  int lane = gid & 63;
  const float4 x4 = *reinterpret_cast<const float4*>(x + (size_t)row * DIM + lane * 4);
  const float4 w4 = *reinterpret_cast<const float4*>(w + lane * 4);
  double dot = (double)x4.x * w4.x + (double)x4.y * w4.y
             + (double)x4.z * w4.z + (double)x4.w * w4.w;
  double w2  = (double)w4.x * w4.x + (double)w4.y * w4.y
             + (double)w4.z * w4.z + (double)w4.w * w4.w;
  #pragma unroll
  for (int off = 32; off > 0; off >>= 1) {
    dot += __shfl_xor(dot, off, 64);
    w2  += __shfl_xor(w2,  off, 64);
  }
  if (lane == 0) {
    float sc = tanhf((float)(dot / sqrt(w2)));
    score[row] = sc;
    u32 b = desc_key(sc) >> 19;
    atomicAdd(&ghist[(u32)((row >> 13) << 13) | b], 1u);   // no return use
  }
}

// ---------------- kernel 2: per-graph exclusive scan + boundary -------------
// 1 block/graph. ghist[g][b] <- bucket start (scatter cursors);
// bends[g][b] <- end; gceil[g] <- end of bucket containing rank KKEEP-1.
__global__ __launch_bounds__(1024) void k_scan(u32* __restrict__ ghist,
                                               u32* __restrict__ bends,
                                               u32* __restrict__ gceil) {
  __shared__ u32 wsum[16];
  const int g    = blockIdx.x;
  const int tid  = threadIdx.x;
  const int wid  = tid >> 6;
  const int lane = tid & 63;
  u32* hg = ghist + ((size_t)g << 13);
  u32* be = bends + ((size_t)g << 13);
  u32 h[8], s = 0;
  #pragma unroll
  for (int j = 0; j < 8; ++j) { h[j] = hg[8 * tid + j]; s += h[j]; }
  u32 inc = s;
  #pragma unroll
  for (int off = 1; off < 64; off <<= 1) {
    u32 t = __shfl_up(inc, off, 64);
    if (lane >= off) inc += t;
  }
  if (lane == 63) wsum[wid] = inc;
  __syncthreads();
  if (tid < 16) {
    u32 v = wsum[tid], vi = v;
    #pragma unroll
    for (int off = 1; off < 16; off <<= 1) {
      u32 t = __shfl_up(vi, off, 64);
      if (tid >= off) vi += t;
    }
    wsum[tid] = vi - v;                      // exclusive wave offset
  }
  __syncthreads();
  u32 run = inc - s + wsum[wid];             // exclusive start of this thread's 8
  #pragma unroll
  for (int j = 0; j < 8; ++j) {
    u32 hv  = h[j];
    u32 end = run + hv;
    hg[8 * tid + j] = run;                   // cursor = bucket start
    be[8 * tid + j] = end;                   // bucket end
    if (run < KKEEP && end >= KKEEP) gceil[g] = end;   // exactly one bucket
    run = end;
  }
}

// ---------------- kernel 3: scatter kept-candidates only --------------------
// 1 thr/node, full occupancy. Dropped buckets (start >= K) -> map16 directly,
// NO returning atomic (kills the drop-side hot bucket). Kept-candidate
// buckets -> cursor atomic + scatter of the one-u32 stable comparator.
__global__ __launch_bounds__(512) void k_scatter(const float* __restrict__ score,
                                                 const u32* __restrict__ bends,
                                                 u32* __restrict__ ghist,
                                                 u32* __restrict__ skey,
                                                 u16* __restrict__ sbkt,
                                                 u16* __restrict__ map16) {
  int node = blockIdx.x * 512 + threadIdx.x;
  int g    = node >> 13;
  int idx  = node & (NPG - 1);
  u32 kd   = desc_key(score[node]);
  u32 b    = kd >> 19;
  size_t gb = ((size_t)g << 13);
  u32 start = b ? bends[gb + b - 1] : 0;     // stable (bends, not cursors)
  if (start >= KKEEP) { map16[gb + idx] = (u16)0xFFFFu; return; }
  u32 pos = atomicAdd(&ghist[gb | b], 1u);
  skey[gb | pos] = (kd << 13) | (u32)idx;
  sbkt[gb | pos] = (u16)b;
}

// ---------------- kernel 4: rank count (kept region only) -------------------
__global__ __launch_bounds__(512) void k_count(const u32* __restrict__ skey,
                                               const u16* __restrict__ sbkt,
                                               const u32* __restrict__ bends,
                                               const u32* __restrict__ gceil,
                                               u16* __restrict__ map16) {
  const int g = blockIdx.x >> 4;
  const int p = (blockIdx.x & 15) * 512 + (int)threadIdx.x;
  if ((u32)p >= gceil[g]) return;            // beyond boundary bucket: not scattered
  const size_t gb = ((size_t)g << 13);
  const u32* skg = skey  + gb;
  const u32* beg = bends + gb;
  u32 key = skg[p];
  u32 b   = sbkt[gb + p];
  u32 start = b ? beg[b - 1] : 0;
  u32 end   = beg[b];
  int idx = (int)(key & 0x1FFFu);
  u32 cnt = 0, q = start;
  for (; q + 4 <= end; q += 4) {             // branchless, wave-broadcast reads
    cnt += (skg[q]     < key) + (skg[q + 1] < key)
         + (skg[q + 2] < key) + (skg[q + 3] < key);
  }
  for (; q < end; ++q) cnt += (skg[q] < key);
  u32 rank = start + cnt;
  map16[gb + idx] = (rank < KKEEP) ? (u16)rank : (u16)0xFFFFu;
}

// ---------------- kernel 5: inverted gather (f32 out) -----------------------
__global__ __launch_bounds__(256) void k_gather(const float* __restrict__ x,
                                                const float* __restrict__ score,
                                                const u16* __restrict__ map16,
                                                float* __restrict__ x_out) {
  int gid  = blockIdx.x * 256 + threadIdx.x;
  int node = gid >> 6;
  int lane = gid & 63;
  u16 rk = map16[node];
  if (rk == 0xFFFFu) return;
  int nid = ((node >> 13) << 12) | (int)rk;  // graph*K + rank
  float val = score[node];
  const float4 v = *reinterpret_cast<const float4*>(x + (size_t)node * DIM + lane * 4);
  float4 o;
  o.x = v.x * val; o.y = v.y * val; o.z = v.z * val; o.w = v.w * val;
  *reinterpret_cast<float4*>(x_out + (size_t)nid * DIM + lane * 4) = o;
}

// ---------------- kernel 6: edges + fused batch_out -------------------------
__global__ __launch_bounds__(256) void k_edges(const int* __restrict__ ei,
                                               const u16* __restrict__ map16,
                                               float* __restrict__ e_out,
                                               float* __restrict__ b_out) {
  int e = blockIdx.x * 256 + threadIdx.x;
  int a = ei[e];
  int b = ei[NEDGE + e];
  u16 ra = map16[a];
  u16 rb = map16[b];
  bool kept = (ra != 0xFFFFu) && (rb != 0xFFFFu);
  e_out[e]         = kept ? (float)(((a >> 13) << 12) | (int)ra) : -1.0f;
  e_out[NEDGE + e] = kept ? (float)(((b >> 13) << 12) | (int)rb) : -1.0f;
  if (e < TOTKEEP) b_out[e] = (float)(e >> 12);   // batch: nid / K = graph id
}

extern "C" void kernel_launch(void* const* d_in, const int* in_sizes, int n_in,
                              void* d_out, int out_size, void* d_ws, size_t ws_size,
                              hipStream_t stream) {
  const float* x  = nullptr;
  const int*   ei = nullptr;
  const float* w  = nullptr;
  for (int i = 0; i < n_in; ++i) {
    if      (in_sizes[i] == TOTALN * DIM) x  = (const float*)d_in[i];
    else if (in_sizes[i] == 2 * NEDGE)    ei = (const int*)d_in[i];
    else if (in_sizes[i] == DIM)          w  = (const float*)d_in[i];
  }
  (void)out_size; (void)ws_size;

  // d_out: FLOAT32, layout [x_out 16777216 | e_out 4194304 | b_out 65536]
  float* out   = (float*)d_out;
  float* x_out = out;
  float* e_out = out + (size_t)TOTKEEP * DIM;
  float* b_out = e_out + 2 * (size_t)NEDGE;

  // staging in d_ws (>=512 MB; every word consumed is written this call)
  char* ws = (char*)d_ws;
  float* score = (float*)(ws);                         // 512 KB
  u32*   ghist = (u32*)(ws + (512 << 10));             // 512 KB
  u32*   bends = (u32*)(ws + (1024 << 10));            // 512 KB
  u32*   skey  = (u32*)(ws + (1536 << 10));            // 512 KB
  u16*   sbkt  = (u16*)(ws + (2048 << 10));            // 256 KB
  u16*   map16 = (u16*)(ws + (2304 << 10));            // 256 KB
  u32*   gceil = (u32*)(ws + (2560 << 10));            // 64 B

  hipLaunchKernelGGL(k_zero,    dim3(TOTALN / 512),  dim3(512),  0, stream, ghist);
  hipLaunchKernelGGL(k_score,   dim3(TOTALN / 4),    dim3(256),  0, stream, x, w, score, ghist);
  hipLaunchKernelGGL(k_scan,    dim3(BGRAPH),        dim3(1024), 0, stream, ghist, bends, gceil);
  hipLaunchKernelGGL(k_scatter, dim3(TOTALN / 512),  dim3(512),  0, stream, score, bends, ghist, skey, sbkt, map16);
  hipLaunchKernelGGL(k_count,   dim3(BGRAPH * 16),   dim3(512),  0, stream, skey, sbkt, bends, gceil, map16);
  hipLaunchKernelGGL(k_gather,  dim3(TOTALN / 4),    dim3(256),  0, stream, x, score, map16, x_out);
  hipLaunchKernelGGL(k_edges,   dim3(NEDGE / 256),   dim3(256),  0, stream, ei, map16, e_out, b_out);
}

// Round 10
// 108.704 us; speedup vs baseline: 1.6075x; 1.6075x over previous
//
#include <hip/hip_runtime.h>

#define BGRAPH  16
#define NPG     8192     // 2^13 nodes per graph
#define DIM     256
#define KKEEP   4096     // 2^12 kept per graph
#define TOTALN  (BGRAPH * NPG)     // 131072
#define TOTKEEP (BGRAPH * KKEEP)   // 65536
#define NEDGE   2097152
#define NBUCK   8192     // 13-bit buckets
#define CHUNKS  4
#define CHSZ    (NPG / CHUNKS)     // 2048

using u16 = unsigned short;
using u32 = unsigned int;

// descending-sortable transform of f32 bits: smaller kd <=> larger float
__device__ __forceinline__ u32 desc_key(float f) {
  u32 b = __float_as_uint(f);
  u32 s = b ^ ((b & 0x80000000u) ? 0xFFFFFFFFu : 0x80000000u);  // asc-sortable
  return ~s;                                                     // desc-sortable
}

// ---------------- kernel 1: score = tanh((x . w) / ||w||) -------------------
// one wave per row (R7 form — NO global atomics; that was R8/R9's regression)
__global__ __launch_bounds__(256) void k_score(const float* __restrict__ x,
                                               const float* __restrict__ w,
                                               float* __restrict__ score) {
  int gid  = blockIdx.x * 256 + threadIdx.x;
  int row  = gid >> 6;
  int lane = gid & 63;
  const float4 x4 = *reinterpret_cast<const float4*>(x + (size_t)row * DIM + lane * 4);
  const float4 w4 = *reinterpret_cast<const float4*>(w + lane * 4);
  double dot = (double)x4.x * w4.x + (double)x4.y * w4.y
             + (double)x4.z * w4.z + (double)x4.w * w4.w;
  double w2  = (double)w4.x * w4.x + (double)w4.y * w4.y
             + (double)w4.z * w4.z + (double)w4.w * w4.w;
  #pragma unroll
  for (int off = 32; off > 0; off >>= 1) {
    dot += __shfl_xor(dot, off, 64);
    w2  += __shfl_xor(w2,  off, 64);
  }
  if (lane == 0) score[row] = tanhf((float)(dot / sqrt(w2)));
}

// ---------------- kernel 2a: per-chunk LDS histogram ------------------------
// 64 blocks (graph g, chunk c); all atomics in LDS (private per block).
__global__ __launch_bounds__(1024) void k_histpart(const float* __restrict__ score,
                                                   u32* __restrict__ hpart) {
  __shared__ u32 hist[NBUCK];                  // 32 KB
  const int g = blockIdx.x >> 2, c = blockIdx.x & 3;
  const int tid = threadIdx.x;
  #pragma unroll
  for (int i = 0; i < NBUCK / 1024; ++i) hist[tid + i * 1024] = 0;
  __syncthreads();
  const float* gs = score + ((size_t)g << 13) + c * CHSZ;
  #pragma unroll
  for (int i = 0; i < CHSZ / 1024; ++i)
    atomicAdd(&hist[desc_key(gs[tid + i * 1024]) >> 19], 1u);
  __syncthreads();
  u32* out = hpart + (((size_t)(g * CHUNKS + c)) << 13);
  #pragma unroll
  for (int i = 0; i < NBUCK / 1024; ++i) out[tid + i * 1024] = hist[tid + i * 1024];
}

// ---------------- kernel 2b: combine + scan + cursors + boundary ------------
// 1 block/graph: tot[b] = sum_c hpart; exclusive scan; per-chunk scatter
// cursors cur[g][c][b]; bends[g][b]; gceil[g] = end of bucket holding rank K-1.
__global__ __launch_bounds__(1024) void k_scan(const u32* __restrict__ hpart,
                                               u32* __restrict__ cur,
                                               u32* __restrict__ bends,
                                               u32* __restrict__ gceil) {
  __shared__ u32 wsum[16];
  const int g    = blockIdx.x;
  const int tid  = threadIdx.x;
  const int wid  = tid >> 6;
  const int lane = tid & 63;
  const u32* hp = hpart + (((size_t)g * CHUNKS) << 13);
  u32* cu = cur   + (((size_t)g * CHUNKS) << 13);
  u32* be = bends + ((size_t)g << 13);

  u32 p0[8], p1[8], p2[8], tot[8]; u32 s = 0;
  #pragma unroll
  for (int j = 0; j < 8; ++j) {
    int b = 8 * tid + j;
    p0[j] = hp[b];
    p1[j] = hp[(1 << 13) + b];
    p2[j] = hp[(2 << 13) + b];
    u32 p3 = hp[(3 << 13) + b];
    tot[j] = p0[j] + p1[j] + p2[j] + p3;
    s += tot[j];
  }
  u32 inc = s;
  #pragma unroll
  for (int off = 1; off < 64; off <<= 1) {
    u32 t = __shfl_up(inc, off, 64);
    if (lane >= off) inc += t;
  }
  if (lane == 63) wsum[wid] = inc;
  __syncthreads();
  if (tid < 16) {
    u32 v = wsum[tid], vi = v;
    #pragma unroll
    for (int off = 1; off < 16; off <<= 1) {
      u32 t = __shfl_up(vi, off, 64);
      if (tid >= off) vi += t;
    }
    wsum[tid] = vi - v;                      // exclusive wave offset
  }
  __syncthreads();
  u32 run = inc - s + wsum[wid];             // exclusive start of this thread's 8
  #pragma unroll
  for (int j = 0; j < 8; ++j) {
    int b = 8 * tid + j;
    u32 st  = run;
    u32 end = st + tot[j];
    cu[b]             = st;
    cu[(1 << 13) + b] = st + p0[j];
    cu[(2 << 13) + b] = st + p0[j] + p1[j];
    cu[(3 << 13) + b] = st + p0[j] + p1[j] + p2[j];
    be[b] = end;
    if (st < KKEEP && end >= KKEEP) gceil[g] = end;   // exactly one bucket
    run = end;
  }
}

// ---------------- kernel 2c: scatter via private LDS cursors ----------------
// 64 blocks (graph g, chunk c): cursors for (g,c) loaded to LDS, bumped there.
// Within-chunk order nondeterministic — harmless: rank is count-based.
__global__ __launch_bounds__(1024) void k_scatter(const float* __restrict__ score,
                                                  const u32* __restrict__ cur,
                                                  u32* __restrict__ skey) {
  __shared__ u32 lcur[NBUCK];                  // 32 KB
  const int g = blockIdx.x >> 2, c = blockIdx.x & 3;
  const int tid = threadIdx.x;
  const u32* cc = cur + (((size_t)(g * CHUNKS + c)) << 13);
  #pragma unroll
  for (int i = 0; i < NBUCK / 1024; ++i) lcur[tid + i * 1024] = cc[tid + i * 1024];
  __syncthreads();
  const float* gs = score + ((size_t)g << 13);
  u32* sk = skey + ((size_t)g << 13);
  #pragma unroll
  for (int i = 0; i < CHSZ / 1024; ++i) {
    int idx = c * CHSZ + tid + i * 1024;
    u32 kd  = desc_key(gs[idx]);
    u32 pos = atomicAdd(&lcur[kd >> 19], 1u);   // LDS atomic (fast)
    sk[pos] = (kd << 13) | (u32)idx;            // stable one-u32 comparator
  }
}

// ---------------- kernel 2d: rank count (full occupancy) --------------------
__global__ __launch_bounds__(512) void k_count(const float* __restrict__ score,
                                               const u32* __restrict__ skey,
                                               const u32* __restrict__ bends,
                                               const u32* __restrict__ gceil,
                                               u16* __restrict__ map16) {
  const int g = blockIdx.x >> 4;
  const int p = (blockIdx.x & 15) * 512 + (int)threadIdx.x;
  const size_t gb = ((size_t)g << 13);
  const u32* skg = skey + gb;
  u32 key = skg[p];
  int idx = (int)(key & 0x1FFFu);
  u16* mp = map16 + gb;
  if ((u32)p >= gceil[g]) { mp[idx] = (u16)0xFFFFu; return; }  // dropped region
  u32 b = desc_key(score[gb + idx]) >> 19;     // bucket from L2-hot re-read
  const u32* beg = bends + gb;
  u32 start = b ? beg[b - 1] : 0;
  u32 end   = beg[b];
  u32 cnt = 0, q = start;
  for (; q + 4 <= end; q += 4) {               // branchless, wave-broadcast reads
    cnt += (skg[q]     < key) + (skg[q + 1] < key)
         + (skg[q + 2] < key) + (skg[q + 3] < key);
  }
  for (; q < end; ++q) cnt += (skg[q] < key);
  u32 rank = start + cnt;
  mp[idx] = (rank < KKEEP) ? (u16)rank : (u16)0xFFFFu;
}

// ---------------- kernel 3: inverted gather (f32 out) -----------------------
__global__ __launch_bounds__(256) void k_gather(const float* __restrict__ x,
                                                const float* __restrict__ score,
                                                const u16* __restrict__ map16,
                                                float* __restrict__ x_out) {
  int gid  = blockIdx.x * 256 + threadIdx.x;
  int node = gid >> 6;
  int lane = gid & 63;
  u16 rk = map16[node];
  if (rk == 0xFFFFu) return;
  int nid = ((node >> 13) << 12) | (int)rk;    // graph*K + rank
  float val = score[node];
  const float4 v = *reinterpret_cast<const float4*>(x + (size_t)node * DIM + lane * 4);
  float4 o;
  o.x = v.x * val; o.y = v.y * val; o.z = v.z * val; o.w = v.w * val;
  *reinterpret_cast<float4*>(x_out + (size_t)nid * DIM + lane * 4) = o;
}

// ---------------- kernel 4: edges (4/thread, vectorized) + fused batch ------
__global__ __launch_bounds__(256) void k_edges(const int* __restrict__ ei,
                                               const u16* __restrict__ map16,
                                               float* __restrict__ e_out,
                                               float* __restrict__ b_out) {
  int t = blockIdx.x * 256 + threadIdx.x;      // handles edges 4t..4t+3
  const int4 a = *reinterpret_cast<const int4*>(ei + 4 * (size_t)t);
  const int4 b = *reinterpret_cast<const int4*>(ei + NEDGE + 4 * (size_t)t);
  u16 ra0 = map16[a.x], ra1 = map16[a.y], ra2 = map16[a.z], ra3 = map16[a.w];
  u16 rb0 = map16[b.x], rb1 = map16[b.y], rb2 = map16[b.z], rb3 = map16[b.w];
  float4 eo0, eo1;
  eo0.x = (ra0 != 0xFFFFu && rb0 != 0xFFFFu) ? (float)(((a.x >> 13) << 12) | ra0) : -1.0f;
  eo0.y = (ra1 != 0xFFFFu && rb1 != 0xFFFFu) ? (float)(((a.y >> 13) << 12) | ra1) : -1.0f;
  eo0.z = (ra2 != 0xFFFFu && rb2 != 0xFFFFu) ? (float)(((a.z >> 13) << 12) | ra2) : -1.0f;
  eo0.w = (ra3 != 0xFFFFu && rb3 != 0xFFFFu) ? (float)(((a.w >> 13) << 12) | ra3) : -1.0f;
  eo1.x = (ra0 != 0xFFFFu && rb0 != 0xFFFFu) ? (float)(((b.x >> 13) << 12) | rb0) : -1.0f;
  eo1.y = (ra1 != 0xFFFFu && rb1 != 0xFFFFu) ? (float)(((b.y >> 13) << 12) | rb1) : -1.0f;
  eo1.z = (ra2 != 0xFFFFu && rb2 != 0xFFFFu) ? (float)(((b.z >> 13) << 12) | rb2) : -1.0f;
  eo1.w = (ra3 != 0xFFFFu && rb3 != 0xFFFFu) ? (float)(((b.w >> 13) << 12) | rb3) : -1.0f;
  *reinterpret_cast<float4*>(e_out + 4 * (size_t)t)         = eo0;
  *reinterpret_cast<float4*>(e_out + NEDGE + 4 * (size_t)t) = eo1;
  if (t < TOTKEEP / 4) {                       // batch: nid / K = graph id
    float4 bo;
    bo.x = (float)((4 * t)     >> 12);
    bo.y = (float)((4 * t + 1) >> 12);
    bo.z = (float)((4 * t + 2) >> 12);
    bo.w = (float)((4 * t + 3) >> 12);
    *reinterpret_cast<float4*>(b_out + 4 * (size_t)t) = bo;
  }
}

extern "C" void kernel_launch(void* const* d_in, const int* in_sizes, int n_in,
                              void* d_out, int out_size, void* d_ws, size_t ws_size,
                              hipStream_t stream) {
  const float* x  = nullptr;
  const int*   ei = nullptr;
  const float* w  = nullptr;
  for (int i = 0; i < n_in; ++i) {
    if      (in_sizes[i] == TOTALN * DIM) x  = (const float*)d_in[i];
    else if (in_sizes[i] == 2 * NEDGE)    ei = (const int*)d_in[i];
    else if (in_sizes[i] == DIM)          w  = (const float*)d_in[i];
  }
  (void)out_size; (void)ws_size;

  // d_out: FLOAT32, layout [x_out 16777216 | e_out 4194304 | b_out 65536]
  float* out   = (float*)d_out;
  float* x_out = out;
  float* e_out = out + (size_t)TOTKEEP * DIM;
  float* b_out = e_out + 2 * (size_t)NEDGE;

  // staging in d_ws (all consumed within this call; fully rewritten each call)
  char* ws = (char*)d_ws;
  float* score = (float*)(ws);                         // 512 KB
  u32*   hpart = (u32*)(ws + (512  << 10));            // 2 MB [16][4][8192]
  u32*   cur   = (u32*)(ws + (2560 << 10));            // 2 MB [16][4][8192]
  u32*   bends = (u32*)(ws + (4608 << 10));            // 512 KB [16][8192]
  u32*   skey  = (u32*)(ws + (5120 << 10));            // 512 KB [16][8192]
  u16*   map16 = (u16*)(ws + (5632 << 10));            // 256 KB
  u32*   gceil = (u32*)(ws + (5888 << 10));            // 64 B

  hipLaunchKernelGGL(k_score,    dim3(TOTALN / 4),      dim3(256),  0, stream, x, w, score);
  hipLaunchKernelGGL(k_histpart, dim3(BGRAPH * CHUNKS), dim3(1024), 0, stream, score, hpart);
  hipLaunchKernelGGL(k_scan,     dim3(BGRAPH),          dim3(1024), 0, stream, hpart, cur, bends, gceil);
  hipLaunchKernelGGL(k_scatter,  dim3(BGRAPH * CHUNKS), dim3(1024), 0, stream, score, cur, skey);
  hipLaunchKernelGGL(k_count,    dim3(BGRAPH * 16),     dim3(512),  0, stream, score, skey, bends, gceil, map16);
  hipLaunchKernelGGL(k_gather,   dim3(TOTALN / 4),      dim3(256),  0, stream, x, score, map16, x_out);
  hipLaunchKernelGGL(k_edges,    dim3(NEDGE / 1024),    dim3(256),  0, stream, ei, map16, e_out, b_out);
}

// Round 11
// 92.841 us; speedup vs baseline: 1.8822x; 1.1709x over previous
//
#include <hip/hip_runtime.h>

#define BGRAPH  16
#define NPG     8192     // 2^13 nodes per graph
#define DIM     256
#define KKEEP   4096     // 2^12 kept per graph
#define TOTALN  (BGRAPH * NPG)     // 131072
#define TOTKEEP (BGRAPH * KKEEP)   // 65536
#define NEDGE   2097152
#define NBUCK   8192     // 13-bit buckets (minimum: skey packing needs low-19 key bits)

using u16 = unsigned short;
using u32 = unsigned int;

// descending-sortable transform of f32 bits: smaller kd <=> larger float
__device__ __forceinline__ u32 desc_key(float f) {
  u32 b = __float_as_uint(f);
  u32 s = b ^ ((b & 0x80000000u) ? 0xFFFFFFFFu : 0x80000000u);  // asc-sortable
  return ~s;                                                     // desc-sortable
}

// ---------------- kernel 1: score = tanh((x . w) / ||w||) -------------------
// one wave per row (proven exact-enough form; NO atomics — R9's lesson)
__global__ __launch_bounds__(256) void k_score(const float* __restrict__ x,
                                               const float* __restrict__ w,
                                               float* __restrict__ score) {
  int gid  = blockIdx.x * 256 + threadIdx.x;
  int row  = gid >> 6;
  int lane = gid & 63;
  const float4 x4 = *reinterpret_cast<const float4*>(x + (size_t)row * DIM + lane * 4);
  const float4 w4 = *reinterpret_cast<const float4*>(w + lane * 4);
  double dot = (double)x4.x * w4.x + (double)x4.y * w4.y
             + (double)x4.z * w4.z + (double)x4.w * w4.w;
  double w2  = (double)w4.x * w4.x + (double)w4.y * w4.y
             + (double)w4.z * w4.z + (double)w4.w * w4.w;
  #pragma unroll
  for (int off = 32; off > 0; off >>= 1) {
    dot += __shfl_xor(dot, off, 64);
    w2  += __shfl_xor(w2,  off, 64);
  }
  if (lane == 0) score[row] = tanhf((float)(dot / sqrt(w2)));
}

// ---------------- kernel 2: monolithic bucket-sort (1 block/graph) ----------
// hist + scan + scatter, all atomics in LDS (R7 structure — best measured).
// Emits: skey[g][pos] = (kd<<13)|idx  (one-u32 stable comparator),
//        bends[g][b]  = bucket end,  gceil[g] = end of bucket holding rank K-1.
__global__ __launch_bounds__(1024) void k_sort(const float* __restrict__ score,
                                               u32* __restrict__ skey,
                                               u32* __restrict__ bends,
                                               u32* __restrict__ gceil) {
  __shared__ u32 hist[NBUCK];                // 32 KB
  __shared__ u32 wsum[16];
  const int g    = blockIdx.x;
  const int tid  = threadIdx.x;
  const int wid  = tid >> 6;
  const int lane = tid & 63;
  const float* gs = score + ((size_t)g << 13);
  u32* skg = skey  + ((size_t)g << 13);
  u32* beg = bends + ((size_t)g << 13);

  // zero histogram
  #pragma unroll
  for (int i = 0; i < NBUCK / 1024; ++i) hist[tid + i * 1024] = 0;
  __syncthreads();

  // histogram (keys cached in registers for the scatter phase)
  u32 kd_[NPG / 1024];
  #pragma unroll
  for (int i = 0; i < NPG / 1024; ++i) {
    kd_[i] = desc_key(gs[tid + i * 1024]);
    atomicAdd(&hist[kd_[i] >> 19], 1u);
  }
  __syncthreads();

  // exclusive prefix sum over 8192 buckets (8/thread + 2-level wave scan);
  // bends + gceil written inline; hist becomes the scatter cursors (starts).
  u32 h[8], s = 0;
  #pragma unroll
  for (int j = 0; j < 8; ++j) { h[j] = hist[8 * tid + j]; s += h[j]; }
  u32 inc = s;
  #pragma unroll
  for (int off = 1; off < 64; off <<= 1) {
    u32 t = __shfl_up(inc, off, 64);
    if (lane >= off) inc += t;
  }
  if (lane == 63) wsum[wid] = inc;
  __syncthreads();
  if (tid < 16) {
    u32 v = wsum[tid], vi = v;
    #pragma unroll
    for (int off = 1; off < 16; off <<= 1) {
      u32 t = __shfl_up(vi, off, 64);
      if (tid >= off) vi += t;
    }
    wsum[tid] = vi - v;                      // exclusive wave offset
  }
  __syncthreads();
  u32 run = inc - s + wsum[wid];             // exclusive start of this thread's 8
  #pragma unroll
  for (int j = 0; j < 8; ++j) {
    u32 hv  = h[j];
    u32 end = run + hv;
    hist[8 * tid + j] = run;                 // cursor = bucket start (own slots only)
    beg[8 * tid + j]  = end;                 // bucket end -> global
    if (run < KKEEP && end >= KKEEP) gceil[g] = end;   // exactly one bucket
    run = end;
  }
  __syncthreads();

  // scatter via LDS cursor atomics; within-bucket order arbitrary (harmless:
  // rank is count-based over the total (key,idx) order)
  #pragma unroll
  for (int i = 0; i < NPG / 1024; ++i) {
    int idx = tid + i * 1024;
    u32 kd  = kd_[i];
    u32 pos = atomicAdd(&hist[kd >> 19], 1u);
    skg[pos] = (kd << 13) | (u32)idx;
  }
}

// ---------------- kernel 3: rank count (full occupancy) ---------------------
__global__ __launch_bounds__(512) void k_count(const float* __restrict__ score,
                                               const u32* __restrict__ skey,
                                               const u32* __restrict__ bends,
                                               const u32* __restrict__ gceil,
                                               u16* __restrict__ map16) {
  const int g = blockIdx.x >> 4;
  const int p = (blockIdx.x & 15) * 512 + (int)threadIdx.x;
  const size_t gb = ((size_t)g << 13);
  const u32* skg = skey + gb;
  u32 key = skg[p];
  int idx = (int)(key & 0x1FFFu);
  u16* mp = map16 + gb;
  if ((u32)p >= gceil[g]) { mp[idx] = (u16)0xFFFFu; return; }  // dropped region
  u32 b = desc_key(score[gb + idx]) >> 19;     // bucket from L1/L2-hot re-read
  const u32* beg = bends + gb;
  u32 start = b ? beg[b - 1] : 0;
  u32 end   = beg[b];
  u32 cnt = 0, q = start;
  for (; q + 4 <= end; q += 4) {               // branchless, wave-broadcast reads
    cnt += (skg[q]     < key) + (skg[q + 1] < key)
         + (skg[q + 2] < key) + (skg[q + 3] < key);
  }
  for (; q < end; ++q) cnt += (skg[q] < key);
  u32 rank = start + cnt;
  mp[idx] = (rank < KKEEP) ? (u16)rank : (u16)0xFFFFu;
}

// ---------------- kernel 4: inverted gather (f32 out) -----------------------
__global__ __launch_bounds__(256) void k_gather(const float* __restrict__ x,
                                                const float* __restrict__ score,
                                                const u16* __restrict__ map16,
                                                float* __restrict__ x_out) {
  int gid  = blockIdx.x * 256 + threadIdx.x;
  int node = gid >> 6;
  int lane = gid & 63;
  u16 rk = map16[node];
  if (rk == 0xFFFFu) return;
  int nid = ((node >> 13) << 12) | (int)rk;    // graph*K + rank
  float val = score[node];
  const float4 v = *reinterpret_cast<const float4*>(x + (size_t)node * DIM + lane * 4);
  float4 o;
  o.x = v.x * val; o.y = v.y * val; o.z = v.z * val; o.w = v.w * val;
  *reinterpret_cast<float4*>(x_out + (size_t)nid * DIM + lane * 4) = o;
}

// ---------------- kernel 5: edges (4/thread, vectorized) + fused batch ------
__global__ __launch_bounds__(256) void k_edges(const int* __restrict__ ei,
                                               const u16* __restrict__ map16,
                                               float* __restrict__ e_out,
                                               float* __restrict__ b_out) {
  int t = blockIdx.x * 256 + threadIdx.x;      // handles edges 4t..4t+3
  const int4 a = *reinterpret_cast<const int4*>(ei + 4 * (size_t)t);
  const int4 b = *reinterpret_cast<const int4*>(ei + NEDGE + 4 * (size_t)t);
  u16 ra0 = map16[a.x], ra1 = map16[a.y], ra2 = map16[a.z], ra3 = map16[a.w];
  u16 rb0 = map16[b.x], rb1 = map16[b.y], rb2 = map16[b.z], rb3 = map16[b.w];
  float4 eo0, eo1;
  eo0.x = (ra0 != 0xFFFFu && rb0 != 0xFFFFu) ? (float)(((a.x >> 13) << 12) | ra0) : -1.0f;
  eo0.y = (ra1 != 0xFFFFu && rb1 != 0xFFFFu) ? (float)(((a.y >> 13) << 12) | ra1) : -1.0f;
  eo0.z = (ra2 != 0xFFFFu && rb2 != 0xFFFFu) ? (float)(((a.z >> 13) << 12) | ra2) : -1.0f;
  eo0.w = (ra3 != 0xFFFFu && rb3 != 0xFFFFu) ? (float)(((a.w >> 13) << 12) | ra3) : -1.0f;
  eo1.x = (ra0 != 0xFFFFu && rb0 != 0xFFFFu) ? (float)(((b.x >> 13) << 12) | rb0) : -1.0f;
  eo1.y = (ra1 != 0xFFFFu && rb1 != 0xFFFFu) ? (float)(((b.y >> 13) << 12) | rb1) : -1.0f;
  eo1.z = (ra2 != 0xFFFFu && rb2 != 0xFFFFu) ? (float)(((b.z >> 13) << 12) | rb2) : -1.0f;
  eo1.w = (ra3 != 0xFFFFu && rb3 != 0xFFFFu) ? (float)(((b.w >> 13) << 12) | rb3) : -1.0f;
  *reinterpret_cast<float4*>(e_out + 4 * (size_t)t)         = eo0;
  *reinterpret_cast<float4*>(e_out + NEDGE + 4 * (size_t)t) = eo1;
  if (t < TOTKEEP / 4) {                       // batch: nid / K = graph id
    float4 bo;
    bo.x = (float)((4 * t)     >> 12);
    bo.y = (float)((4 * t + 1) >> 12);
    bo.z = (float)((4 * t + 2) >> 12);
    bo.w = (float)((4 * t + 3) >> 12);
    *reinterpret_cast<float4*>(b_out + 4 * (size_t)t) = bo;
  }
}

extern "C" void kernel_launch(void* const* d_in, const int* in_sizes, int n_in,
                              void* d_out, int out_size, void* d_ws, size_t ws_size,
                              hipStream_t stream) {
  const float* x  = nullptr;
  const int*   ei = nullptr;
  const float* w  = nullptr;
  for (int i = 0; i < n_in; ++i) {
    if      (in_sizes[i] == TOTALN * DIM) x  = (const float*)d_in[i];
    else if (in_sizes[i] == 2 * NEDGE)    ei = (const int*)d_in[i];
    else if (in_sizes[i] == DIM)          w  = (const float*)d_in[i];
  }
  (void)out_size; (void)ws_size;

  // d_out: FLOAT32, layout [x_out 16777216 | e_out 4194304 | b_out 65536]
  float* out   = (float*)d_out;
  float* x_out = out;
  float* e_out = out + (size_t)TOTKEEP * DIM;
  float* b_out = e_out + 2 * (size_t)NEDGE;

  // staging in d_ws (every consumed word is written earlier in this call)
  char* ws = (char*)d_ws;
  float* score = (float*)(ws);                         // 512 KB
  u32*   skey  = (u32*)(ws + (512  << 10));            // 512 KB [16][8192]
  u32*   bends = (u32*)(ws + (1024 << 10));            // 512 KB [16][8192]
  u16*   map16 = (u16*)(ws + (1536 << 10));            // 256 KB
  u32*   gceil = (u32*)(ws + (1792 << 10));            // 64 B

  hipLaunchKernelGGL(k_score,  dim3(TOTALN / 4),  dim3(256),  0, stream, x, w, score);
  hipLaunchKernelGGL(k_sort,   dim3(BGRAPH),      dim3(1024), 0, stream, score, skey, bends, gceil);
  hipLaunchKernelGGL(k_count,  dim3(BGRAPH * 16), dim3(512),  0, stream, score, skey, bends, gceil, map16);
  hipLaunchKernelGGL(k_gather, dim3(TOTALN / 4),  dim3(256),  0, stream, x, score, map16, x_out);
  hipLaunchKernelGGL(k_edges,  dim3(NEDGE / 1024),dim3(256),  0, stream, ei, map16, e_out, b_out);
}

// Round 12
// 91.116 us; speedup vs baseline: 1.9178x; 1.0189x over previous
//
#include <hip/hip_runtime.h>

#define BGRAPH  16
#define NPG     8192     // 2^13 nodes per graph
#define DIM     256
#define KKEEP   4096     // 2^12 kept per graph
#define TOTALN  (BGRAPH * NPG)     // 131072
#define TOTKEEP (BGRAPH * KKEEP)   // 65536
#define NEDGE   2097152
#define NBUCK   8192     // 13-bit buckets (skey packs low-19 key bits + 13-bit idx)
#define SCHUNK  8        // sort blocks per graph

using u16 = unsigned short;
using u32 = unsigned int;

// descending-sortable transform of f32 bits: smaller kd <=> larger float
__device__ __forceinline__ u32 desc_key(float f) {
  u32 b = __float_as_uint(f);
  u32 s = b ^ ((b & 0x80000000u) ? 0xFFFFFFFFu : 0x80000000u);  // asc-sortable
  return ~s;                                                     // desc-sortable
}

// ---------------- kernel 1: score = tanh((x . w) / ||w||) -------------------
// one wave per row (proven form; NO atomics — R9's lesson)
__global__ __launch_bounds__(256) void k_score(const float* __restrict__ x,
                                               const float* __restrict__ w,
                                               float* __restrict__ score) {
  int gid  = blockIdx.x * 256 + threadIdx.x;
  int row  = gid >> 6;
  int lane = gid & 63;
  const float4 x4 = *reinterpret_cast<const float4*>(x + (size_t)row * DIM + lane * 4);
  const float4 w4 = *reinterpret_cast<const float4*>(w + lane * 4);
  double dot = (double)x4.x * w4.x + (double)x4.y * w4.y
             + (double)x4.z * w4.z + (double)x4.w * w4.w;
  double w2  = (double)w4.x * w4.x + (double)w4.y * w4.y
             + (double)w4.z * w4.z + (double)w4.w * w4.w;
  #pragma unroll
  for (int off = 32; off > 0; off >>= 1) {
    dot += __shfl_xor(dot, off, 64);
    w2  += __shfl_xor(w2,  off, 64);
  }
  if (lane == 0) score[row] = tanhf((float)(dot / sqrt(w2)));
}

// ---------------- kernel 2: 8-way parallel bucket-sort ----------------------
// SCHUNK blocks per graph; each block is SELF-SUFFICIENT (redundant full hist
// + scan — replicated compute instead of cross-block traffic, which R10
// proved slow). acc[b] counts elements of PRIOR chunks in bucket b, so
// cursor = start[b] + acc[b] gives each block a private disjoint slot range.
// All atomics in LDS. Each block scatters only its 1024 elements.
__global__ __launch_bounds__(1024) void k_sort(const float* __restrict__ score,
                                               u32* __restrict__ skey,
                                               u32* __restrict__ bends,
                                               u32* __restrict__ gceil) {
  __shared__ u32 hist[NBUCK];                // 32 KB (counts -> scratch -> starts)
  __shared__ u32 acc[NBUCK];                 // 32 KB (prior-chunk counts -> cursors)
  const int g    = blockIdx.x >> 3;
  const int c    = blockIdx.x & (SCHUNK - 1);
  const int tid  = threadIdx.x;
  const int wid  = tid >> 6;
  const int lane = tid & 63;
  const float* gs = score + ((size_t)g << 13);
  u32* skg = skey  + ((size_t)g << 13);
  u32* beg = bends + ((size_t)g << 13);

  #pragma unroll
  for (int i = 0; i < NBUCK / 1024; ++i) {
    hist[tid + i * 1024] = 0;
    acc[tid + i * 1024]  = 0;
  }
  __syncthreads();

  // full histogram (all 8 chunks) + prior-chunk counts; own key kept in reg
  u32 mykd = 0;
  #pragma unroll
  for (int c2 = 0; c2 < SCHUNK; ++c2) {
    u32 kd = desc_key(gs[c2 * 1024 + tid]);
    atomicAdd(&hist[kd >> 19], 1u);
    if (c2 == c) mykd = kd;
    if (c2 < c)  atomicAdd(&acc[kd >> 19], 1u);
  }
  __syncthreads();

  // exclusive scan of 8192 buckets; hist doubles as scan scratch (counts are
  // in regs after the barrier), then is rewritten with bucket STARTS.
  u32 h[8], s = 0;
  #pragma unroll
  for (int j = 0; j < 8; ++j) { h[j] = hist[8 * tid + j]; s += h[j]; }
  __syncthreads();                           // all counts in regs; hist = scratch
  u32 inc = s;
  #pragma unroll
  for (int off = 1; off < 64; off <<= 1) {
    u32 t = __shfl_up(inc, off, 64);
    if (lane >= off) inc += t;
  }
  if (lane == 63) hist[wid] = inc;           // 16 wave totals
  __syncthreads();
  if (tid < 16) {
    u32 v = hist[tid], vi = v;
    #pragma unroll
    for (int off = 1; off < 16; off <<= 1) {
      u32 t = __shfl_up(vi, off, 64);
      if (tid >= off) vi += t;
    }
    hist[tid] = vi - v;                      // exclusive wave offset
  }
  __syncthreads();
  u32 excl = inc - s + hist[wid];
  __syncthreads();                           // wave offsets read; hist reusable
  u32 run = excl;
  #pragma unroll
  for (int j = 0; j < 8; ++j) {
    u32 end = run + h[j];
    hist[8 * tid + j] = run;                 // bucket start
    if (c == 0) {
      beg[8 * tid + j] = end;                // bends -> global (one block/graph)
      if (run < KKEEP && end >= KKEEP) gceil[g] = end;
    }
    run = end;
  }
  __syncthreads();

  // cursors = start + prior-chunk count
  #pragma unroll
  for (int i = 0; i < NBUCK / 1024; ++i) {
    int b = tid + i * 1024;
    acc[b] += hist[b];
  }
  __syncthreads();

  // scatter own chunk (1 element/thread)
  u32 pos = atomicAdd(&acc[mykd >> 19], 1u);
  skg[pos] = (mykd << 13) | (u32)(c * 1024 + tid);
}

// ---------------- kernel 3: rank count (full occupancy) ---------------------
__global__ __launch_bounds__(512) void k_count(const float* __restrict__ score,
                                               const u32* __restrict__ skey,
                                               const u32* __restrict__ bends,
                                               const u32* __restrict__ gceil,
                                               u16* __restrict__ map16) {
  const int g = blockIdx.x >> 4;
  const int p = (blockIdx.x & 15) * 512 + (int)threadIdx.x;
  const size_t gb = ((size_t)g << 13);
  const u32* skg = skey + gb;
  u32 key = skg[p];
  int idx = (int)(key & 0x1FFFu);
  u16* mp = map16 + gb;
  if ((u32)p >= gceil[g]) { mp[idx] = (u16)0xFFFFu; return; }  // dropped region
  u32 b = desc_key(score[gb + idx]) >> 19;     // bucket from L1/L2-hot re-read
  const u32* beg = bends + gb;
  u32 start = b ? beg[b - 1] : 0;
  u32 end   = beg[b];
  u32 cnt = 0, q = start;
  for (; q + 4 <= end; q += 4) {               // branchless, wave-broadcast reads
    cnt += (skg[q]     < key) + (skg[q + 1] < key)
         + (skg[q + 2] < key) + (skg[q + 3] < key);
  }
  for (; q < end; ++q) cnt += (skg[q] < key);
  u32 rank = start + cnt;
  mp[idx] = (rank < KKEEP) ? (u16)rank : (u16)0xFFFFu;
}

// ---------------- kernel 4: inverted gather (f32 out) -----------------------
__global__ __launch_bounds__(256) void k_gather(const float* __restrict__ x,
                                                const float* __restrict__ score,
                                                const u16* __restrict__ map16,
                                                float* __restrict__ x_out) {
  int gid  = blockIdx.x * 256 + threadIdx.x;
  int node = gid >> 6;
  int lane = gid & 63;
  u16 rk = map16[node];
  if (rk == 0xFFFFu) return;
  int nid = ((node >> 13) << 12) | (int)rk;    // graph*K + rank
  float val = score[node];
  const float4 v = *reinterpret_cast<const float4*>(x + (size_t)node * DIM + lane * 4);
  float4 o;
  o.x = v.x * val; o.y = v.y * val; o.z = v.z * val; o.w = v.w * val;
  *reinterpret_cast<float4*>(x_out + (size_t)nid * DIM + lane * 4) = o;
}

// ---------------- kernel 5: edges (4/thread, vectorized) + fused batch ------
__global__ __launch_bounds__(256) void k_edges(const int* __restrict__ ei,
                                               const u16* __restrict__ map16,
                                               float* __restrict__ e_out,
                                               float* __restrict__ b_out) {
  int t = blockIdx.x * 256 + threadIdx.x;      // handles edges 4t..4t+3
  const int4 a = *reinterpret_cast<const int4*>(ei + 4 * (size_t)t);
  const int4 b = *reinterpret_cast<const int4*>(ei + NEDGE + 4 * (size_t)t);
  u16 ra0 = map16[a.x], ra1 = map16[a.y], ra2 = map16[a.z], ra3 = map16[a.w];
  u16 rb0 = map16[b.x], rb1 = map16[b.y], rb2 = map16[b.z], rb3 = map16[b.w];
  float4 eo0, eo1;
  eo0.x = (ra0 != 0xFFFFu && rb0 != 0xFFFFu) ? (float)(((a.x >> 13) << 12) | ra0) : -1.0f;
  eo0.y = (ra1 != 0xFFFFu && rb1 != 0xFFFFu) ? (float)(((a.y >> 13) << 12) | ra1) : -1.0f;
  eo0.z = (ra2 != 0xFFFFu && rb2 != 0xFFFFu) ? (float)(((a.z >> 13) << 12) | ra2) : -1.0f;
  eo0.w = (ra3 != 0xFFFFu && rb3 != 0xFFFFu) ? (float)(((a.w >> 13) << 12) | ra3) : -1.0f;
  eo1.x = (ra0 != 0xFFFFu && rb0 != 0xFFFFu) ? (float)(((b.x >> 13) << 12) | rb0) : -1.0f;
  eo1.y = (ra1 != 0xFFFFu && rb1 != 0xFFFFu) ? (float)(((b.y >> 13) << 12) | rb1) : -1.0f;
  eo1.z = (ra2 != 0xFFFFu && rb2 != 0xFFFFu) ? (float)(((b.z >> 13) << 12) | rb2) : -1.0f;
  eo1.w = (ra3 != 0xFFFFu && rb3 != 0xFFFFu) ? (float)(((b.w >> 13) << 12) | rb3) : -1.0f;
  *reinterpret_cast<float4*>(e_out + 4 * (size_t)t)         = eo0;
  *reinterpret_cast<float4*>(e_out + NEDGE + 4 * (size_t)t) = eo1;
  if (t < TOTKEEP / 4) {                       // batch: nid / K = graph id
    float4 bo;
    bo.x = (float)((4 * t)     >> 12);
    bo.y = (float)((4 * t + 1) >> 12);
    bo.z = (float)((4 * t + 2) >> 12);
    bo.w = (float)((4 * t + 3) >> 12);
    *reinterpret_cast<float4*>(b_out + 4 * (size_t)t) = bo;
  }
}

extern "C" void kernel_launch(void* const* d_in, const int* in_sizes, int n_in,
                              void* d_out, int out_size, void* d_ws, size_t ws_size,
                              hipStream_t stream) {
  const float* x  = nullptr;
  const int*   ei = nullptr;
  const float* w  = nullptr;
  for (int i = 0; i < n_in; ++i) {
    if      (in_sizes[i] == TOTALN * DIM) x  = (const float*)d_in[i];
    else if (in_sizes[i] == 2 * NEDGE)    ei = (const int*)d_in[i];
    else if (in_sizes[i] == DIM)          w  = (const float*)d_in[i];
  }
  (void)out_size; (void)ws_size;

  // d_out: FLOAT32, layout [x_out 16777216 | e_out 4194304 | b_out 65536]
  float* out   = (float*)d_out;
  float* x_out = out;
  float* e_out = out + (size_t)TOTKEEP * DIM;
  float* b_out = e_out + 2 * (size_t)NEDGE;

  // staging in d_ws (every consumed word is written earlier in this call)
  char* ws = (char*)d_ws;
  float* score = (float*)(ws);                         // 512 KB
  u32*   skey  = (u32*)(ws + (512  << 10));            // 512 KB [16][8192]
  u32*   bends = (u32*)(ws + (1024 << 10));            // 512 KB [16][8192]
  u16*   map16 = (u16*)(ws + (1536 << 10));            // 256 KB
  u32*   gceil = (u32*)(ws + (1792 << 10));            // 64 B

  hipLaunchKernelGGL(k_score,  dim3(TOTALN / 4),        dim3(256),  0, stream, x, w, score);
  hipLaunchKernelGGL(k_sort,   dim3(BGRAPH * SCHUNK),   dim3(1024), 0, stream, score, skey, bends, gceil);
  hipLaunchKernelGGL(k_count,  dim3(BGRAPH * 16),       dim3(512),  0, stream, score, skey, bends, gceil, map16);
  hipLaunchKernelGGL(k_gather, dim3(TOTALN / 4),        dim3(256),  0, stream, x, score, map16, x_out);
  hipLaunchKernelGGL(k_edges,  dim3(NEDGE / 1024),      dim3(256),  0, stream, ei, map16, e_out, b_out);
}